// Round 1
// baseline (303.497 us; speedup 1.0000x reference)
//
#include <hip/hip_runtime.h>

#define N_NODES 50000
#define N_EDGES 800000

// ---------------------------------------------------------------------------
// Kernel 1: per-node  h = [x@Wf.T+bf (32) | reg_emb[reg] (16) | dep_emb[dep] (16)]
//           p1 = h @ W1_l.T  (16),  r1 = h @ W1_r.T  (16)
// 8 nodes per 256-thread block; 32 threads per node (one per output column).
// Weights staged transposed in LDS so the inner dot is bank-conflict-free.
// ---------------------------------------------------------------------------
__global__ __launch_bounds__(256) void node1_kernel(
    const float* __restrict__ x, const int* __restrict__ reg_id,
    const int* __restrict__ dep_id,
    const float* __restrict__ W_feat, const float* __restrict__ b_feat,
    const float* __restrict__ reg_emb, const float* __restrict__ dep_emb,
    const float* __restrict__ W1_l, const float* __restrict__ W1_r,
    float* __restrict__ p1, float* __restrict__ r1)
{
    __shared__ float sWt[128 * 32];   // W_feat transposed: [k][j]
    __shared__ float sW1t[64 * 32];   // rows j<16: W1_l, j>=16: W1_r; transposed [k][j]
    __shared__ float sx[8 * 128];
    __shared__ float sh[8 * 64];

    const int tid = threadIdx.x;
    for (int i = tid; i < 128 * 32; i += 256) {
        int k = i >> 5, j = i & 31;
        sWt[i] = W_feat[j * 128 + k];
    }
    for (int i = tid; i < 64 * 32; i += 256) {
        int k = i >> 5, j = i & 31;
        sW1t[i] = (j < 16) ? W1_l[j * 64 + k] : W1_r[(j - 16) * 64 + k];
    }
    const int node0 = blockIdx.x * 8;
    for (int i = tid; i < 8 * 128; i += 256) {
        int n = node0 + (i >> 7);
        sx[i] = (n < N_NODES) ? x[n * 128 + (i & 127)] : 0.f;
    }
    __syncthreads();

    const int nl = tid >> 5;        // node-local 0..7
    const int j  = tid & 31;        // output column 0..31
    const int n  = node0 + nl;
    if (n < N_NODES) {
        float acc = b_feat[j];
        #pragma unroll 8
        for (int k = 0; k < 128; ++k) acc += sx[nl * 128 + k] * sWt[k * 32 + j];
        sh[nl * 64 + j] = acc;
        if (j < 16) sh[nl * 64 + 32 + j] = reg_emb[reg_id[n] * 16 + j];
        else        sh[nl * 64 + 32 + j] = dep_emb[dep_id[n] * 16 + (j - 16)];
    }
    __syncthreads();

    if (n < N_NODES) {
        float acc = 0.f;
        #pragma unroll
        for (int k = 0; k < 64; ++k) acc += sh[nl * 64 + k] * sW1t[k * 32 + j];
        if (j < 16) p1[n * 16 + j]        = acc;   // b1_l folded in later
        else        r1[n * 16 + (j - 16)] = acc;
    }
}

// ---------------------------------------------------------------------------
// Kernel 2: edge scatter for layer 1 (16 floats/edge) + in-degree count
// ---------------------------------------------------------------------------
__global__ __launch_bounds__(256) void agg1_kernel(
    const int* __restrict__ ei, const float* __restrict__ p1,
    float* __restrict__ agg1, float* __restrict__ cnt)
{
    int t = blockIdx.x * 256 + threadIdx.x;   // max 12.8M, fits int
    int e = t >> 4, f = t & 15;
    if (e < N_EDGES) {
        int s = ei[e];
        int d = ei[N_EDGES + e];
        atomicAdd(&agg1[d * 16 + f], p1[s * 16 + f]);
        if (f == 0) atomicAdd(&cnt[d], 1.0f);
    }
}

// ---------------------------------------------------------------------------
// Kernel 3: h1 = relu(agg1/max(cnt,1) + b1_l + r1);  p2 = h1@W2_l.T, r2 = h1@W2_r.T
// 4 nodes per block; 64 threads per node (one per output: 32 p2 + 32 r2).
// ---------------------------------------------------------------------------
__global__ __launch_bounds__(256) void node2_kernel(
    const float* __restrict__ agg1, const float* __restrict__ cnt,
    const float* __restrict__ r1, const float* __restrict__ b1_l,
    const float* __restrict__ W2_l, const float* __restrict__ W2_r,
    float* __restrict__ p2, float* __restrict__ r2)
{
    __shared__ float sW2t[16 * 64];  // cols r<32: W2_l rows, r>=32: W2_r rows; [k][r]
    __shared__ float sh1[4 * 16];

    const int tid = threadIdx.x;
    for (int i = tid; i < 16 * 64; i += 256) {
        int k = i >> 6, r = i & 63;
        sW2t[i] = (r < 32) ? W2_l[r * 16 + k] : W2_r[(r - 32) * 16 + k];
    }
    const int node0 = blockIdx.x * 4;
    const int nl = tid >> 6;        // 0..3
    const int j  = tid & 63;        // 0..63
    const int n  = node0 + nl;
    if (n < N_NODES && j < 16) {
        float c = fmaxf(cnt[n], 1.0f);
        float v = agg1[n * 16 + j] / c + b1_l[j] + r1[n * 16 + j];
        sh1[nl * 16 + j] = fmaxf(v, 0.0f);
    }
    __syncthreads();
    if (n < N_NODES) {
        float acc = 0.f;
        #pragma unroll
        for (int k = 0; k < 16; ++k) acc += sh1[nl * 16 + k] * sW2t[k * 64 + j];
        if (j < 32) p2[n * 32 + j]        = acc;   // b2_l folded in later
        else        r2[n * 32 + (j - 32)] = acc;
    }
}

// ---------------------------------------------------------------------------
// Kernel 4: edge scatter for layer 2 (32 floats/edge)
// ---------------------------------------------------------------------------
__global__ __launch_bounds__(256) void agg2_kernel(
    const int* __restrict__ ei, const float* __restrict__ p2,
    float* __restrict__ agg2)
{
    int t = blockIdx.x * 256 + threadIdx.x;   // max 25.6M, fits int
    int e = t >> 5, f = t & 31;
    if (e < N_EDGES) {
        int s = ei[e];
        int d = ei[N_EDGES + e];
        atomicAdd(&agg2[d * 32 + f], p2[s * 32 + f]);
    }
}

// ---------------------------------------------------------------------------
// Kernel 5: out = relu(agg2/max(cnt,1) + b2_l + r2) @ W_lin.T + b_lin
// 32 threads per node, shuffle reduce within the 32-lane group.
// ---------------------------------------------------------------------------
__global__ __launch_bounds__(256) void final_kernel(
    const float* __restrict__ agg2, const float* __restrict__ cnt,
    const float* __restrict__ r2, const float* __restrict__ b2_l,
    const float* __restrict__ W_lin, const float* __restrict__ b_lin,
    float* __restrict__ out)
{
    int t = blockIdx.x * 256 + threadIdx.x;
    int n = t >> 5, f = t & 31;
    if (n >= N_NODES) return;     // grid is exact (50000*32/256 = 6250), no partial groups
    float c = fmaxf(cnt[n], 1.0f);
    float v = fmaxf(agg2[n * 32 + f] / c + b2_l[f] + r2[n * 32 + f], 0.f) * W_lin[f];
    #pragma unroll
    for (int off = 16; off; off >>= 1) v += __shfl_xor(v, off, 32);
    if (f == 0) out[n] = v + b_lin[0];
}

extern "C" void kernel_launch(void* const* d_in, const int* in_sizes, int n_in,
                              void* d_out, int out_size, void* d_ws, size_t ws_size,
                              hipStream_t stream) {
    const float* x       = (const float*)d_in[0];
    const int*   ei      = (const int*)  d_in[1];   // [2, E] : src row then dst row
    const int*   reg_id  = (const int*)  d_in[2];
    const int*   dep_id  = (const int*)  d_in[3];
    const float* W_feat  = (const float*)d_in[4];
    const float* b_feat  = (const float*)d_in[5];
    const float* reg_emb = (const float*)d_in[6];
    const float* dep_emb = (const float*)d_in[7];
    const float* W1_l    = (const float*)d_in[8];
    const float* b1_l    = (const float*)d_in[9];
    const float* W1_r    = (const float*)d_in[10];
    const float* W2_l    = (const float*)d_in[11];
    const float* b2_l    = (const float*)d_in[12];
    const float* W2_r    = (const float*)d_in[13];
    const float* W_lin   = (const float*)d_in[14];
    const float* b_lin   = (const float*)d_in[15];
    float* out = (float*)d_out;
    float* ws  = (float*)d_ws;

    const int N = N_NODES;
    // workspace layout (floats): total 145*N = 29 MB
    float* cnt  = ws;            // [N]
    float* agg1 = ws + N;        // [N,16]
    float* p1   = ws + 17 * N;   // [N,16]
    float* r1   = ws + 33 * N;   // [N,16]
    float* agg2 = ws + 49 * N;   // [N,32]
    float* p2   = ws + 81 * N;   // [N,32]
    float* r2   = ws + 113 * N;  // [N,32]

    // zero the accumulators (cnt+agg1 contiguous, agg2 separate)
    hipMemsetAsync(cnt,  0, (size_t)17 * N * sizeof(float), stream);
    hipMemsetAsync(agg2, 0, (size_t)32 * N * sizeof(float), stream);

    node1_kernel<<<(N + 7) / 8, 256, 0, stream>>>(
        x, reg_id, dep_id, W_feat, b_feat, reg_emb, dep_emb, W1_l, W1_r, p1, r1);

    agg1_kernel<<<(N_EDGES * 16 + 255) / 256, 256, 0, stream>>>(ei, p1, agg1, cnt);

    node2_kernel<<<(N + 3) / 4, 256, 0, stream>>>(
        agg1, cnt, r1, b1_l, W2_l, W2_r, p2, r2);

    agg2_kernel<<<(N_EDGES * 32 + 255) / 256, 256, 0, stream>>>(ei, p2, agg2);

    final_kernel<<<(N * 32 + 255) / 256, 256, 0, stream>>>(
        agg2, cnt, r2, b2_l, W_lin, b_lin, out);
}

// Round 2
// 202.097 us; speedup vs baseline: 1.5017x; 1.5017x over previous
//
#include <hip/hip_runtime.h>

#define N_NODES 50000
#define N_EDGES 800000
#define SCAN_BLK 1024
#define SCAN_NBLK ((N_NODES + SCAN_BLK - 1) / SCAN_BLK)   // 49

// ---------------------------------------------------------------------------
// node1: 64 nodes/block, 256 threads. Wave w computes output cols j0=8w..8w+7
// for all 64 nodes. Weights read via wave-uniform indices -> s_load (SGPR),
// x staged in LDS (padded stride 132) read as float4.
//   sh row = [ x@Wf.T+bf (32) | reg_emb (16) | dep_emb (16) ]   (stride 68)
//   p1 = sh @ W1_l.T, r1 = sh @ W1_r.T
// ---------------------------------------------------------------------------
__global__ __launch_bounds__(256) void node1_kernel(
    const float* __restrict__ x, const int* __restrict__ reg_id,
    const int* __restrict__ dep_id,
    const float* __restrict__ W_feat, const float* __restrict__ b_feat,
    const float* __restrict__ reg_emb, const float* __restrict__ dep_emb,
    const float* __restrict__ W1_l, const float* __restrict__ W1_r,
    float* __restrict__ p1, float* __restrict__ r1)
{
    __shared__ float sx[64 * 132];   // x rows, padded stride 132
    __shared__ float sh[64 * 68];    // h rows, padded stride 68

    const int tid = threadIdx.x;
    const int node0 = blockIdx.x * 64;

    // stage x: 2048 float4, coalesced
    for (int i = tid; i < 64 * 32; i += 256) {
        int row = i >> 5, c4 = i & 31;
        float4 v = make_float4(0.f, 0.f, 0.f, 0.f);
        int n = node0 + row;
        if (n < N_NODES) v = *(const float4*)&x[n * 128 + c4 * 4];
        *(float4*)&sx[row * 132 + c4 * 4] = v;
    }
    // stage embeddings into sh cols 32..63
    for (int i = tid; i < 64 * 16; i += 256) {
        int r = i >> 4, f = i & 15;
        int n = node0 + r;
        if (n < N_NODES) {
            sh[r * 68 + 32 + f] = reg_emb[reg_id[n] * 16 + f];
            sh[r * 68 + 48 + f] = dep_emb[dep_id[n] * 16 + f];
        }
    }
    __syncthreads();

    const int nl = tid & 63;
    const int j0 = __builtin_amdgcn_readfirstlane((tid >> 6) * 8);  // wave-uniform

    // GEMM1: sh[nl][j0..j0+7] = x[nl] . W_feat[j0+jj] + b_feat
    {
        float acc[8];
        #pragma unroll
        for (int jj = 0; jj < 8; ++jj) acc[jj] = b_feat[j0 + jj];
        #pragma unroll 4
        for (int k = 0; k < 128; k += 4) {
            float4 xv = *(const float4*)&sx[nl * 132 + k];
            #pragma unroll
            for (int jj = 0; jj < 8; ++jj) {
                const float* wr = &W_feat[(j0 + jj) * 128 + k];
                acc[jj] += xv.x * wr[0] + xv.y * wr[1] + xv.z * wr[2] + xv.w * wr[3];
            }
        }
        #pragma unroll
        for (int jj = 0; jj < 8; ++jj) sh[nl * 68 + j0 + jj] = acc[jj];
    }
    __syncthreads();

    // GEMM2: 64 -> 32 (16 p1 cols + 16 r1 cols), wave-uniform W rows
    {
        const float* Wbase = (j0 < 16) ? (W1_l + j0 * 64) : (W1_r + (j0 - 16) * 64);
        float acc[8];
        #pragma unroll
        for (int jj = 0; jj < 8; ++jj) acc[jj] = 0.f;
        #pragma unroll 4
        for (int k = 0; k < 64; k += 4) {
            float4 hv = *(const float4*)&sh[nl * 68 + k];
            #pragma unroll
            for (int jj = 0; jj < 8; ++jj) {
                const float* wr = &Wbase[jj * 64 + k];
                acc[jj] += hv.x * wr[0] + hv.y * wr[1] + hv.z * wr[2] + hv.w * wr[3];
            }
        }
        int n = node0 + nl;
        if (n < N_NODES) {
            float* outp = (j0 < 16) ? (p1 + n * 16 + j0) : (r1 + n * 16 + (j0 - 16));
            *(float4*)outp       = make_float4(acc[0], acc[1], acc[2], acc[3]);
            *(float4*)(outp + 4) = make_float4(acc[4], acc[5], acc[6], acc[7]);
        }
    }
}

// ---------------------------------------------------------------------------
// CSR build: histogram -> 3-step exclusive scan -> fill
// ---------------------------------------------------------------------------
__global__ __launch_bounds__(256) void hist_kernel(
    const int* __restrict__ ei, int* __restrict__ deg)
{
    int t = blockIdx.x * 256 + threadIdx.x;
    if (t < N_EDGES) atomicAdd(&deg[ei[N_EDGES + t]], 1);
}

__global__ __launch_bounds__(SCAN_BLK) void scan1_kernel(
    const int* __restrict__ deg, int* __restrict__ rowp, int* __restrict__ parts)
{
    __shared__ int buf[2][SCAN_BLK];
    int t = threadIdx.x;
    int i = blockIdx.x * SCAN_BLK + t;
    int v = (i < N_NODES) ? deg[i] : 0;
    int cur = 0;
    buf[0][t] = v;
    __syncthreads();
    for (int off = 1; off < SCAN_BLK; off <<= 1) {
        int nv = buf[cur][t] + ((t >= off) ? buf[cur][t - off] : 0);
        buf[cur ^ 1][t] = nv;
        cur ^= 1;
        __syncthreads();
    }
    int incl = buf[cur][t];
    if (i < N_NODES) rowp[i] = incl - v;           // block-local exclusive
    if (t == SCAN_BLK - 1) parts[blockIdx.x] = incl;
}

__global__ void scan2_kernel(const int* __restrict__ parts, int* __restrict__ poff)
{
    int t = threadIdx.x;   // 64 threads, one wave
    int orig = (t < SCAN_NBLK) ? parts[t] : 0;
    int v = orig;
    #pragma unroll
    for (int off = 1; off < 64; off <<= 1) {
        int u = __shfl_up(v, off, 64);
        if (t >= off) v += u;
    }
    if (t < SCAN_NBLK) poff[t] = v - orig;         // exclusive
}

__global__ __launch_bounds__(SCAN_BLK) void scan3_kernel(
    int* __restrict__ rowp, const int* __restrict__ poff)
{
    int i = blockIdx.x * SCAN_BLK + threadIdx.x;
    if (i < N_NODES) rowp[i] += poff[blockIdx.x];
}

__global__ __launch_bounds__(256) void fill_kernel(
    const int* __restrict__ ei, const int* __restrict__ rowp,
    int* __restrict__ fillc, int* __restrict__ csrc)
{
    int t = blockIdx.x * 256 + threadIdx.x;
    if (t < N_EDGES) {
        int d = ei[N_EDGES + t];
        int pos = rowp[d] + atomicAdd(&fillc[d], 1);
        csrc[pos] = ei[t];
    }
}

// ---------------------------------------------------------------------------
// gather1: h1[n][f] = relu( mean_{s in N(n)} p1[s][f] + b1_l[f] + r1[n][f] )
// 16 threads per node (f = 0..15), 16 nodes per block.
// ---------------------------------------------------------------------------
__global__ __launch_bounds__(256) void gather1_kernel(
    const int* __restrict__ rowp, const int* __restrict__ csrc,
    const float* __restrict__ p1, const float* __restrict__ r1,
    const float* __restrict__ b1_l, float* __restrict__ h1)
{
    int t = blockIdx.x * 256 + threadIdx.x;
    int n = t >> 4, f = t & 15;
    if (n >= N_NODES) return;
    int start = rowp[n];
    int end = (n + 1 < N_NODES) ? rowp[n + 1] : N_EDGES;
    float acc = 0.f;
    for (int e = start; e < end; ++e) {
        int s = csrc[e];
        acc += p1[s * 16 + f];
    }
    float c = (float)(end - start);
    float mean = acc / fmaxf(c, 1.0f);
    h1[n * 16 + f] = fmaxf(mean + b1_l[f] + r1[n * 16 + f], 0.f);
}

// ---------------------------------------------------------------------------
// node2: p2 = h1 @ W2_l.T, r2 = h1 @ W2_r.T   (same scalar-W pattern as node1)
// 64 nodes/block; wave w -> 16 outputs (w0,w1: p2 cols; w2,w3: r2 cols)
// ---------------------------------------------------------------------------
__global__ __launch_bounds__(256) void node2_kernel(
    const float* __restrict__ h1, const float* __restrict__ W2_l,
    const float* __restrict__ W2_r, float* __restrict__ p2, float* __restrict__ r2)
{
    __shared__ float sh1[64 * 20];   // padded stride 20

    const int tid = threadIdx.x;
    const int node0 = blockIdx.x * 64;
    for (int i = tid; i < 256; i += 256) {
        int row = i >> 2, c4 = i & 3;
        float4 v = make_float4(0.f, 0.f, 0.f, 0.f);
        int n = node0 + row;
        if (n < N_NODES) v = *(const float4*)&h1[n * 16 + c4 * 4];
        *(float4*)&sh1[row * 20 + c4 * 4] = v;
    }
    __syncthreads();

    const int nl = tid & 63;
    const int w  = __builtin_amdgcn_readfirstlane(tid >> 6);
    const int j0 = (w & 1) * 16;
    const float* Wbase = (w < 2) ? (W2_l + j0 * 16) : (W2_r + j0 * 16);

    float acc[16];
    #pragma unroll
    for (int jj = 0; jj < 16; ++jj) acc[jj] = 0.f;
    #pragma unroll
    for (int k = 0; k < 16; k += 4) {
        float4 hv = *(const float4*)&sh1[nl * 20 + k];
        #pragma unroll
        for (int jj = 0; jj < 16; ++jj) {
            const float* wr = &Wbase[jj * 16 + k];
            acc[jj] += hv.x * wr[0] + hv.y * wr[1] + hv.z * wr[2] + hv.w * wr[3];
        }
    }
    int n = node0 + nl;
    if (n < N_NODES) {
        float* outp = (w < 2) ? (p2 + n * 32 + j0) : (r2 + n * 32 + j0);
        #pragma unroll
        for (int q = 0; q < 4; ++q)
            *(float4*)(outp + q * 4) =
                make_float4(acc[q * 4], acc[q * 4 + 1], acc[q * 4 + 2], acc[q * 4 + 3]);
    }
}

// ---------------------------------------------------------------------------
// gather2 + final: h2 = relu(mean p2 + b2_l + r2); out = h2 . W_lin + b_lin
// 32 threads per node, shuffle-reduce the final dot.
// ---------------------------------------------------------------------------
__global__ __launch_bounds__(256) void gather2_kernel(
    const int* __restrict__ rowp, const int* __restrict__ csrc,
    const float* __restrict__ p2, const float* __restrict__ r2,
    const float* __restrict__ b2_l, const float* __restrict__ W_lin,
    const float* __restrict__ b_lin, float* __restrict__ out)
{
    int t = blockIdx.x * 256 + threadIdx.x;
    int n = t >> 5, f = t & 31;
    if (n >= N_NODES) return;
    int start = rowp[n];
    int end = (n + 1 < N_NODES) ? rowp[n + 1] : N_EDGES;
    float acc = 0.f;
    for (int e = start; e < end; ++e) {
        int s = csrc[e];
        acc += p2[s * 32 + f];
    }
    float c = (float)(end - start);
    float mean = acc / fmaxf(c, 1.0f);
    float h2 = fmaxf(mean + b2_l[f] + r2[n * 32 + f], 0.f);
    float v = h2 * W_lin[f];
    #pragma unroll
    for (int off = 16; off; off >>= 1) v += __shfl_xor(v, off, 32);
    if (f == 0) out[n] = v + b_lin[0];
}

extern "C" void kernel_launch(void* const* d_in, const int* in_sizes, int n_in,
                              void* d_out, int out_size, void* d_ws, size_t ws_size,
                              hipStream_t stream) {
    const float* x       = (const float*)d_in[0];
    const int*   ei      = (const int*)  d_in[1];
    const int*   reg_id  = (const int*)  d_in[2];
    const int*   dep_id  = (const int*)  d_in[3];
    const float* W_feat  = (const float*)d_in[4];
    const float* b_feat  = (const float*)d_in[5];
    const float* reg_emb = (const float*)d_in[6];
    const float* dep_emb = (const float*)d_in[7];
    const float* W1_l    = (const float*)d_in[8];
    const float* b1_l    = (const float*)d_in[9];
    const float* W1_r    = (const float*)d_in[10];
    const float* W2_l    = (const float*)d_in[11];
    const float* b2_l    = (const float*)d_in[12];
    const float* W2_r    = (const float*)d_in[13];
    const float* W_lin   = (const float*)d_in[14];
    const float* b_lin   = (const float*)d_in[15];
    float* out = (float*)d_out;
    float* ws  = (float*)d_ws;

    const int N = N_NODES;
    // workspace layout
    float* p1 = ws;              // [N,16]
    float* r1 = ws + 16 * N;     // [N,16]
    float* h1 = ws + 32 * N;     // [N,16]
    float* p2 = ws + 48 * N;     // [N,32]
    float* r2 = ws + 80 * N;     // [N,32]
    int* ideg  = (int*)(ws + 112 * N);  // [N]
    int* fillc = ideg + N;              // [N]   (memset together with ideg)
    int* rowp  = ideg + 2 * N;          // [N]
    int* csrc  = ideg + 3 * N;          // [E]
    int* parts = csrc + N_EDGES;        // [64]
    int* poff  = parts + 64;            // [64]

    hipMemsetAsync(ideg, 0, (size_t)2 * N * sizeof(int), stream);

    node1_kernel<<<(N + 63) / 64, 256, 0, stream>>>(
        x, reg_id, dep_id, W_feat, b_feat, reg_emb, dep_emb, W1_l, W1_r, p1, r1);

    hist_kernel<<<(N_EDGES + 255) / 256, 256, 0, stream>>>(ei, ideg);
    scan1_kernel<<<SCAN_NBLK, SCAN_BLK, 0, stream>>>(ideg, rowp, parts);
    scan2_kernel<<<1, 64, 0, stream>>>(parts, poff);
    scan3_kernel<<<SCAN_NBLK, SCAN_BLK, 0, stream>>>(rowp, poff);
    fill_kernel<<<(N_EDGES + 255) / 256, 256, 0, stream>>>(ei, rowp, fillc, csrc);

    gather1_kernel<<<(N * 16 + 255) / 256, 256, 0, stream>>>(
        rowp, csrc, p1, r1, b1_l, h1);

    node2_kernel<<<(N + 63) / 64, 256, 0, stream>>>(h1, W2_l, W2_r, p2, r2);

    gather2_kernel<<<(N * 32 + 255) / 256, 256, 0, stream>>>(
        rowp, csrc, p2, r2, b2_l, W_lin, b_lin, out);
}

// Round 3
// 178.439 us; speedup vs baseline: 1.7008x; 1.1326x over previous
//
#include <hip/hip_runtime.h>

#define N_NODES 50000
#define N_EDGES 800000
#define SCAN_BLK 1024
#define SCAN_NBLK ((N_NODES + SCAN_BLK - 1) / SCAN_BLK)   // 49

// ---------------------------------------------------------------------------
// node1: 64 nodes/block, 256 threads. Wave w computes output cols j0=8w..8w+7
// for all 64 nodes. Weight indices are wave-uniform -> s_load (SGPR),
// x staged in LDS (padded stride 132) read as float4.
//   sh row = [ x@Wf.T+bf (32) | reg_emb (16) | dep_emb (16) ]   (stride 68)
//   p1 = sh @ W1_l.T, r1 = sh @ W1_r.T
// ---------------------------------------------------------------------------
__global__ __launch_bounds__(256) void node1_kernel(
    const float* __restrict__ x, const int* __restrict__ reg_id,
    const int* __restrict__ dep_id,
    const float* __restrict__ W_feat, const float* __restrict__ b_feat,
    const float* __restrict__ reg_emb, const float* __restrict__ dep_emb,
    const float* __restrict__ W1_l, const float* __restrict__ W1_r,
    float* __restrict__ p1, float* __restrict__ r1)
{
    __shared__ float sx[64 * 132];   // x rows, padded stride 132
    __shared__ float sh[64 * 68];    // h rows, padded stride 68

    const int tid = threadIdx.x;
    const int node0 = blockIdx.x * 64;

    for (int i = tid; i < 64 * 32; i += 256) {
        int row = i >> 5, c4 = i & 31;
        float4 v = make_float4(0.f, 0.f, 0.f, 0.f);
        int n = node0 + row;
        if (n < N_NODES) v = *(const float4*)&x[n * 128 + c4 * 4];
        *(float4*)&sx[row * 132 + c4 * 4] = v;
    }
    for (int i = tid; i < 64 * 16; i += 256) {
        int r = i >> 4, f = i & 15;
        int n = node0 + r;
        if (n < N_NODES) {
            sh[r * 68 + 32 + f] = reg_emb[reg_id[n] * 16 + f];
            sh[r * 68 + 48 + f] = dep_emb[dep_id[n] * 16 + f];
        }
    }
    __syncthreads();

    const int nl = tid & 63;
    const int j0 = __builtin_amdgcn_readfirstlane((tid >> 6) * 8);  // wave-uniform

    {
        float acc[8];
        #pragma unroll
        for (int jj = 0; jj < 8; ++jj) acc[jj] = b_feat[j0 + jj];
        #pragma unroll 4
        for (int k = 0; k < 128; k += 4) {
            float4 xv = *(const float4*)&sx[nl * 132 + k];
            #pragma unroll
            for (int jj = 0; jj < 8; ++jj) {
                const float* wr = &W_feat[(j0 + jj) * 128 + k];
                acc[jj] += xv.x * wr[0] + xv.y * wr[1] + xv.z * wr[2] + xv.w * wr[3];
            }
        }
        #pragma unroll
        for (int jj = 0; jj < 8; ++jj) sh[nl * 68 + j0 + jj] = acc[jj];
    }
    __syncthreads();

    {
        const float* Wbase = (j0 < 16) ? (W1_l + j0 * 64) : (W1_r + (j0 - 16) * 64);
        float acc[8];
        #pragma unroll
        for (int jj = 0; jj < 8; ++jj) acc[jj] = 0.f;
        #pragma unroll 4
        for (int k = 0; k < 64; k += 4) {
            float4 hv = *(const float4*)&sh[nl * 68 + k];
            #pragma unroll
            for (int jj = 0; jj < 8; ++jj) {
                const float* wr = &Wbase[jj * 64 + k];
                acc[jj] += hv.x * wr[0] + hv.y * wr[1] + hv.z * wr[2] + hv.w * wr[3];
            }
        }
        int n = node0 + nl;
        if (n < N_NODES) {
            float* outp = (j0 < 16) ? (p1 + n * 16 + j0) : (r1 + n * 16 + (j0 - 16));
            *(float4*)outp       = make_float4(acc[0], acc[1], acc[2], acc[3]);
            *(float4*)(outp + 4) = make_float4(acc[4], acc[5], acc[6], acc[7]);
        }
    }
}

// ---------------------------------------------------------------------------
// CSR build. hist: degree histogram AND per-edge rank (the atomic's return
// value IS the rank — fill needs no atomics after this).
// ---------------------------------------------------------------------------
__global__ __launch_bounds__(256) void hist_kernel(
    const int* __restrict__ ei, int* __restrict__ deg, int* __restrict__ rank)
{
    int t = blockIdx.x * 256 + threadIdx.x;
    if (t < N_EDGES) rank[t] = atomicAdd(&deg[ei[N_EDGES + t]], 1);
}

__global__ __launch_bounds__(SCAN_BLK) void scan1_kernel(
    const int* __restrict__ deg, int* __restrict__ rowp, int* __restrict__ parts)
{
    __shared__ int buf[2][SCAN_BLK];
    int t = threadIdx.x;
    int i = blockIdx.x * SCAN_BLK + t;
    int v = (i < N_NODES) ? deg[i] : 0;
    int cur = 0;
    buf[0][t] = v;
    __syncthreads();
    for (int off = 1; off < SCAN_BLK; off <<= 1) {
        int nv = buf[cur][t] + ((t >= off) ? buf[cur][t - off] : 0);
        buf[cur ^ 1][t] = nv;
        cur ^= 1;
        __syncthreads();
    }
    int incl = buf[cur][t];
    if (i < N_NODES) rowp[i] = incl - v;           // block-local exclusive
    if (t == SCAN_BLK - 1) parts[blockIdx.x] = incl;
}

__global__ void scan2_kernel(const int* __restrict__ parts, int* __restrict__ poff)
{
    int t = threadIdx.x;   // 64 threads, one wave
    int orig = (t < SCAN_NBLK) ? parts[t] : 0;
    int v = orig;
    #pragma unroll
    for (int off = 1; off < 64; off <<= 1) {
        int u = __shfl_up(v, off, 64);
        if (t >= off) v += u;
    }
    if (t < SCAN_NBLK) poff[t] = v - orig;         // exclusive
}

__global__ __launch_bounds__(SCAN_BLK) void scan3_kernel(
    int* __restrict__ rowp, const int* __restrict__ poff)
{
    int i = blockIdx.x * SCAN_BLK + threadIdx.x;
    if (i < N_NODES) rowp[i] += poff[blockIdx.x];
}

// atomic-free fill: pos = rowp[dst] + rank (rowp is 200KB, L2-hot)
__global__ __launch_bounds__(256) void fill_kernel(
    const int* __restrict__ ei, const int* __restrict__ rowp,
    const int* __restrict__ rank, int* __restrict__ csrc)
{
    int t = blockIdx.x * 256 + threadIdx.x;
    if (t < N_EDGES) {
        int d = ei[N_EDGES + t];
        csrc[rowp[d] + rank[t]] = ei[t];
    }
}

// ---------------------------------------------------------------------------
// gather1: h1[n][f] = relu( mean_{s in N(n)} p1[s][f] + b1_l[f] + r1[n][f] )
// ---------------------------------------------------------------------------
__global__ __launch_bounds__(256) void gather1_kernel(
    const int* __restrict__ rowp, const int* __restrict__ csrc,
    const float* __restrict__ p1, const float* __restrict__ r1,
    const float* __restrict__ b1_l, float* __restrict__ h1)
{
    int t = blockIdx.x * 256 + threadIdx.x;
    int n = t >> 4, f = t & 15;
    if (n >= N_NODES) return;
    int start = rowp[n];
    int end = (n + 1 < N_NODES) ? rowp[n + 1] : N_EDGES;
    float acc = 0.f;
    for (int e = start; e < end; ++e) {
        int s = csrc[e];
        acc += p1[s * 16 + f];
    }
    float c = (float)(end - start);
    float mean = acc / fmaxf(c, 1.0f);
    h1[n * 16 + f] = fmaxf(mean + b1_l[f] + r1[n * 16 + f], 0.f);
}

// ---------------------------------------------------------------------------
// node2: p2 = h1 @ W2_l.T, r2 = h1 @ W2_r.T
// ---------------------------------------------------------------------------
__global__ __launch_bounds__(256) void node2_kernel(
    const float* __restrict__ h1, const float* __restrict__ W2_l,
    const float* __restrict__ W2_r, float* __restrict__ p2, float* __restrict__ r2)
{
    __shared__ float sh1[64 * 20];   // padded stride 20

    const int tid = threadIdx.x;
    const int node0 = blockIdx.x * 64;
    {
        int row = tid >> 2, c4 = tid & 3;
        float4 v = make_float4(0.f, 0.f, 0.f, 0.f);
        int n = node0 + row;
        if (n < N_NODES) v = *(const float4*)&h1[n * 16 + c4 * 4];
        *(float4*)&sh1[row * 20 + c4 * 4] = v;
    }
    __syncthreads();

    const int nl = tid & 63;
    const int w  = __builtin_amdgcn_readfirstlane(tid >> 6);
    const int j0 = (w & 1) * 16;
    const float* Wbase = (w < 2) ? (W2_l + j0 * 16) : (W2_r + j0 * 16);

    float acc[16];
    #pragma unroll
    for (int jj = 0; jj < 16; ++jj) acc[jj] = 0.f;
    #pragma unroll
    for (int k = 0; k < 16; k += 4) {
        float4 hv = *(const float4*)&sh1[nl * 20 + k];
        #pragma unroll
        for (int jj = 0; jj < 16; ++jj) {
            const float* wr = &Wbase[jj * 16 + k];
            acc[jj] += hv.x * wr[0] + hv.y * wr[1] + hv.z * wr[2] + hv.w * wr[3];
        }
    }
    int n = node0 + nl;
    if (n < N_NODES) {
        float* outp = (w < 2) ? (p2 + n * 32 + j0) : (r2 + n * 32 + j0);
        #pragma unroll
        for (int q = 0; q < 4; ++q)
            *(float4*)(outp + q * 4) =
                make_float4(acc[q * 4], acc[q * 4 + 1], acc[q * 4 + 2], acc[q * 4 + 3]);
    }
}

// ---------------------------------------------------------------------------
// gather2 + final: h2 = relu(mean p2 + b2_l + r2); out = h2 . W_lin + b_lin
// ---------------------------------------------------------------------------
__global__ __launch_bounds__(256) void gather2_kernel(
    const int* __restrict__ rowp, const int* __restrict__ csrc,
    const float* __restrict__ p2, const float* __restrict__ r2,
    const float* __restrict__ b2_l, const float* __restrict__ W_lin,
    const float* __restrict__ b_lin, float* __restrict__ out)
{
    int t = blockIdx.x * 256 + threadIdx.x;
    int n = t >> 5, f = t & 31;
    if (n >= N_NODES) return;
    int start = rowp[n];
    int end = (n + 1 < N_NODES) ? rowp[n + 1] : N_EDGES;
    float acc = 0.f;
    for (int e = start; e < end; ++e) {
        int s = csrc[e];
        acc += p2[s * 32 + f];
    }
    float c = (float)(end - start);
    float mean = acc / fmaxf(c, 1.0f);
    float h2 = fmaxf(mean + b2_l[f] + r2[n * 32 + f], 0.f);
    float v = h2 * W_lin[f];
    #pragma unroll
    for (int off = 16; off; off >>= 1) v += __shfl_xor(v, off, 32);
    if (f == 0) out[n] = v + b_lin[0];
}

extern "C" void kernel_launch(void* const* d_in, const int* in_sizes, int n_in,
                              void* d_out, int out_size, void* d_ws, size_t ws_size,
                              hipStream_t stream) {
    const float* x       = (const float*)d_in[0];
    const int*   ei      = (const int*)  d_in[1];
    const int*   reg_id  = (const int*)  d_in[2];
    const int*   dep_id  = (const int*)  d_in[3];
    const float* W_feat  = (const float*)d_in[4];
    const float* b_feat  = (const float*)d_in[5];
    const float* reg_emb = (const float*)d_in[6];
    const float* dep_emb = (const float*)d_in[7];
    const float* W1_l    = (const float*)d_in[8];
    const float* b1_l    = (const float*)d_in[9];
    const float* W1_r    = (const float*)d_in[10];
    const float* W2_l    = (const float*)d_in[11];
    const float* b2_l    = (const float*)d_in[12];
    const float* W2_r    = (const float*)d_in[13];
    const float* W_lin   = (const float*)d_in[14];
    const float* b_lin   = (const float*)d_in[15];
    float* out = (float*)d_out;
    float* ws  = (float*)d_ws;

    const int N = N_NODES;
    // workspace layout (floats):
    //   [0,16N)   p1   -> later reused as p2[0:16N)
    //   [16N,32N) r1   -> later reused as p2[16N:32N)
    //   [32N,48N) h1
    //   [48N,80N) r2
    // p2 overlays p1+r1: gather1 (the only consumer of p1/r1) completes
    // before node2 writes p2 — same-stream ordering makes this safe.
    float* p1 = ws;
    float* r1 = ws + 16 * N;
    float* h1 = ws + 32 * N;
    float* p2 = ws;              // overlay
    float* r2 = ws + 48 * N;
    int* ideg  = (int*)(ws + 80 * N);   // [N]
    int* rowp  = ideg + N;              // [N]
    int* rank  = ideg + 2 * N;          // [E]
    int* csrc  = rank + N_EDGES;        // [E]
    int* parts = csrc + N_EDGES;        // [64]
    int* poff  = parts + 64;            // [64]

    hipMemsetAsync(ideg, 0, (size_t)N * sizeof(int), stream);

    node1_kernel<<<(N + 63) / 64, 256, 0, stream>>>(
        x, reg_id, dep_id, W_feat, b_feat, reg_emb, dep_emb, W1_l, W1_r, p1, r1);

    hist_kernel<<<(N_EDGES + 255) / 256, 256, 0, stream>>>(ei, ideg, rank);
    scan1_kernel<<<SCAN_NBLK, SCAN_BLK, 0, stream>>>(ideg, rowp, parts);
    scan2_kernel<<<1, 64, 0, stream>>>(parts, poff);
    scan3_kernel<<<SCAN_NBLK, SCAN_BLK, 0, stream>>>(rowp, poff);
    fill_kernel<<<(N_EDGES + 255) / 256, 256, 0, stream>>>(ei, rowp, rank, csrc);

    gather1_kernel<<<(N * 16 + 255) / 256, 256, 0, stream>>>(
        rowp, csrc, p1, r1, b1_l, h1);

    node2_kernel<<<(N + 63) / 64, 256, 0, stream>>>(h1, W2_l, W2_r, p2, r2);

    gather2_kernel<<<(N * 32 + 255) / 256, 256, 0, stream>>>(
        rowp, csrc, p2, r2, b2_l, W_lin, b_lin, out);
}

// Round 4
// 136.833 us; speedup vs baseline: 2.2180x; 1.3041x over previous
//
#include <hip/hip_runtime.h>

#define N_NODES 50000
#define N_EDGES 800000
#define SCAN_BLK 1024
#define SCAN_NBLK ((N_NODES + SCAN_BLK - 1) / SCAN_BLK)   // 49

// ---------------------------------------------------------------------------
// node1: 64 nodes/block, 256 threads. Wave w computes output cols j0=8w..8w+7
// for all 64 nodes. Weight indices wave-uniform -> s_load; x staged in LDS.
//   sh row = [ x@Wf.T+bf (32) | reg_emb (16) | dep_emb (16) ]
//   p1 = sh @ W1_l.T, r1 = sh @ W1_r.T
// ---------------------------------------------------------------------------
__global__ __launch_bounds__(256) void node1_kernel(
    const float* __restrict__ x, const int* __restrict__ reg_id,
    const int* __restrict__ dep_id,
    const float* __restrict__ W_feat, const float* __restrict__ b_feat,
    const float* __restrict__ reg_emb, const float* __restrict__ dep_emb,
    const float* __restrict__ W1_l, const float* __restrict__ W1_r,
    float* __restrict__ p1, float* __restrict__ r1)
{
    __shared__ float sx[64 * 132];   // padded stride 132 (132/4 odd -> 2-way max)
    __shared__ float sh[64 * 68];

    const int tid = threadIdx.x;
    const int node0 = blockIdx.x * 64;

    for (int i = tid; i < 64 * 32; i += 256) {
        int row = i >> 5, c4 = i & 31;
        float4 v = make_float4(0.f, 0.f, 0.f, 0.f);
        int n = node0 + row;
        if (n < N_NODES) v = *(const float4*)&x[n * 128 + c4 * 4];
        *(float4*)&sx[row * 132 + c4 * 4] = v;
    }
    for (int i = tid; i < 64 * 16; i += 256) {
        int r = i >> 4, f = i & 15;
        int n = node0 + r;
        if (n < N_NODES) {
            sh[r * 68 + 32 + f] = reg_emb[reg_id[n] * 16 + f];
            sh[r * 68 + 48 + f] = dep_emb[dep_id[n] * 16 + f];
        }
    }
    __syncthreads();

    const int nl = tid & 63;
    const int j0 = __builtin_amdgcn_readfirstlane((tid >> 6) * 8);  // wave-uniform

    {
        float acc[8];
        #pragma unroll
        for (int jj = 0; jj < 8; ++jj) acc[jj] = b_feat[j0 + jj];
        #pragma unroll 4
        for (int k = 0; k < 128; k += 4) {
            float4 xv = *(const float4*)&sx[nl * 132 + k];
            #pragma unroll
            for (int jj = 0; jj < 8; ++jj) {
                const float* wr = &W_feat[(j0 + jj) * 128 + k];
                acc[jj] += xv.x * wr[0] + xv.y * wr[1] + xv.z * wr[2] + xv.w * wr[3];
            }
        }
        #pragma unroll
        for (int jj = 0; jj < 8; ++jj) sh[nl * 68 + j0 + jj] = acc[jj];
    }
    __syncthreads();

    {
        const float* Wbase = (j0 < 16) ? (W1_l + j0 * 64) : (W1_r + (j0 - 16) * 64);
        float acc[8];
        #pragma unroll
        for (int jj = 0; jj < 8; ++jj) acc[jj] = 0.f;
        #pragma unroll 4
        for (int k = 0; k < 64; k += 4) {
            float4 hv = *(const float4*)&sh[nl * 68 + k];
            #pragma unroll
            for (int jj = 0; jj < 8; ++jj) {
                const float* wr = &Wbase[jj * 64 + k];
                acc[jj] += hv.x * wr[0] + hv.y * wr[1] + hv.z * wr[2] + hv.w * wr[3];
            }
        }
        int n = node0 + nl;
        if (n < N_NODES) {
            float* outp = (j0 < 16) ? (p1 + n * 16 + j0) : (r1 + n * 16 + (j0 - 16));
            *(float4*)outp       = make_float4(acc[0], acc[1], acc[2], acc[3]);
            *(float4*)(outp + 4) = make_float4(acc[4], acc[5], acc[6], acc[7]);
        }
    }
}

// ---------------------------------------------------------------------------
// CSR build: hist (atomic return = per-edge rank) -> scan -> atomic-free fill
// ---------------------------------------------------------------------------
__global__ __launch_bounds__(256) void hist_kernel(
    const int* __restrict__ ei, int* __restrict__ deg, int* __restrict__ rank)
{
    int t = blockIdx.x * 256 + threadIdx.x;
    if (t < N_EDGES) rank[t] = atomicAdd(&deg[ei[N_EDGES + t]], 1);
}

__global__ __launch_bounds__(SCAN_BLK) void scan1_kernel(
    const int* __restrict__ deg, int* __restrict__ rowp, int* __restrict__ parts)
{
    __shared__ int buf[2][SCAN_BLK];
    int t = threadIdx.x;
    int i = blockIdx.x * SCAN_BLK + t;
    int v = (i < N_NODES) ? deg[i] : 0;
    int cur = 0;
    buf[0][t] = v;
    __syncthreads();
    for (int off = 1; off < SCAN_BLK; off <<= 1) {
        int nv = buf[cur][t] + ((t >= off) ? buf[cur][t - off] : 0);
        buf[cur ^ 1][t] = nv;
        cur ^= 1;
        __syncthreads();
    }
    int incl = buf[cur][t];
    if (i < N_NODES) rowp[i] = incl - v;
    if (t == SCAN_BLK - 1) parts[blockIdx.x] = incl;
}

__global__ void scan2_kernel(const int* __restrict__ parts, int* __restrict__ poff)
{
    int t = threadIdx.x;   // one wave
    int orig = (t < SCAN_NBLK) ? parts[t] : 0;
    int v = orig;
    #pragma unroll
    for (int off = 1; off < 64; off <<= 1) {
        int u = __shfl_up(v, off, 64);
        if (t >= off) v += u;
    }
    if (t < SCAN_NBLK) poff[t] = v - orig;
}

__global__ __launch_bounds__(SCAN_BLK) void scan3_kernel(
    int* __restrict__ rowp, const int* __restrict__ poff)
{
    int i = blockIdx.x * SCAN_BLK + threadIdx.x;
    if (i < N_NODES) rowp[i] += poff[blockIdx.x];
}

__global__ __launch_bounds__(256) void fill_kernel(
    const int* __restrict__ ei, const int* __restrict__ rowp,
    const int* __restrict__ rank, int* __restrict__ csrc)
{
    int t = blockIdx.x * 256 + threadIdx.x;
    if (t < N_EDGES) {
        int d = ei[N_EDGES + t];
        csrc[rowp[d] + rank[t]] = ei[t];
    }
}

// ---------------------------------------------------------------------------
// gather1: one wave per node. 16 edge slots x float4. All lanes end with the
// slot-summed float4 for cols f4*4..+3; slot 0 applies mean+bias+res+relu.
// ---------------------------------------------------------------------------
__global__ __launch_bounds__(256) void gather1_kernel(
    const int* __restrict__ rowp, const int* __restrict__ csrc,
    const float* __restrict__ p1, const float* __restrict__ r1,
    const float* __restrict__ b1_l, float* __restrict__ h1)
{
    int n = (blockIdx.x * 256 + threadIdx.x) >> 6;   // grid exact: 12500 blocks
    if (n >= N_NODES) return;
    int lane = threadIdx.x & 63;
    int slot = lane >> 2, f4 = lane & 3;
    int start = rowp[n];
    int end = (n + 1 < N_NODES) ? rowp[n + 1] : N_EDGES;

    float4 acc = make_float4(0.f, 0.f, 0.f, 0.f);
    for (int e0 = start; e0 < end; e0 += 16) {
        int e = e0 + slot;
        if (e < end) {
            float4 v = *(const float4*)&p1[csrc[e] * 16 + f4 * 4];
            acc.x += v.x; acc.y += v.y; acc.z += v.z; acc.w += v.w;
        }
    }
    #pragma unroll
    for (int off = 4; off <= 32; off <<= 1) {
        acc.x += __shfl_xor(acc.x, off, 64);
        acc.y += __shfl_xor(acc.y, off, 64);
        acc.z += __shfl_xor(acc.z, off, 64);
        acc.w += __shfl_xor(acc.w, off, 64);
    }
    if (slot == 0) {
        float inv = 1.0f / fmaxf((float)(end - start), 1.0f);
        float4 rv = *(const float4*)&r1[n * 16 + f4 * 4];
        float4 bv = *(const float4*)&b1_l[f4 * 4];
        float4 o;
        o.x = fmaxf(acc.x * inv + bv.x + rv.x, 0.f);
        o.y = fmaxf(acc.y * inv + bv.y + rv.y, 0.f);
        o.z = fmaxf(acc.z * inv + bv.z + rv.z, 0.f);
        o.w = fmaxf(acc.w * inv + bv.w + rv.w, 0.f);
        *(float4*)&h1[n * 16 + f4 * 4] = o;
    }
}

// ---------------------------------------------------------------------------
// gather2 + node2 + final, fused. One wave per node:
//   m2 = mean_{s in N(n)} h1[s]        (16 slots x float4, butterfly reduce)
//   h2 = relu(m2 @ W2_l.T + b2 + h1[n] @ W2_r.T)   (jpair=lane>>2, f4 butterfly)
//   out[n] = h2 . W_lin + b_lin                     (jpair butterfly)
// ---------------------------------------------------------------------------
__global__ __launch_bounds__(256) void gather2_kernel(
    const int* __restrict__ rowp, const int* __restrict__ csrc,
    const float* __restrict__ h1,
    const float* __restrict__ W2_l, const float* __restrict__ b2_l,
    const float* __restrict__ W2_r, const float* __restrict__ W_lin,
    const float* __restrict__ b_lin, float* __restrict__ out)
{
    int n = (blockIdx.x * 256 + threadIdx.x) >> 6;
    if (n >= N_NODES) return;
    int lane = threadIdx.x & 63;
    int slot = lane >> 2, f4 = lane & 3;
    int start = rowp[n];
    int end = (n + 1 < N_NODES) ? rowp[n + 1] : N_EDGES;

    float4 acc = make_float4(0.f, 0.f, 0.f, 0.f);
    for (int e0 = start; e0 < end; e0 += 16) {
        int e = e0 + slot;
        if (e < end) {
            float4 v = *(const float4*)&h1[csrc[e] * 16 + f4 * 4];
            acc.x += v.x; acc.y += v.y; acc.z += v.z; acc.w += v.w;
        }
    }
    #pragma unroll
    for (int off = 4; off <= 32; off <<= 1) {
        acc.x += __shfl_xor(acc.x, off, 64);
        acc.y += __shfl_xor(acc.y, off, 64);
        acc.z += __shfl_xor(acc.z, off, 64);
        acc.w += __shfl_xor(acc.w, off, 64);
    }
    float inv = 1.0f / fmaxf((float)(end - start), 1.0f);
    float4 m2 = make_float4(acc.x * inv, acc.y * inv, acc.z * inv, acc.w * inv);
    float4 hn = *(const float4*)&h1[n * 16 + f4 * 4];

    int j0 = slot * 2;                               // 0,2,..,30
    float4 wl0 = *(const float4*)&W2_l[j0 * 16 + f4 * 4];
    float4 wl1 = *(const float4*)&W2_l[(j0 + 1) * 16 + f4 * 4];
    float4 wr0 = *(const float4*)&W2_r[j0 * 16 + f4 * 4];
    float4 wr1 = *(const float4*)&W2_r[(j0 + 1) * 16 + f4 * 4];

    float pa = m2.x * wl0.x + m2.y * wl0.y + m2.z * wl0.z + m2.w * wl0.w
             + hn.x * wr0.x + hn.y * wr0.y + hn.z * wr0.z + hn.w * wr0.w;
    float pb = m2.x * wl1.x + m2.y * wl1.y + m2.z * wl1.z + m2.w * wl1.w
             + hn.x * wr1.x + hn.y * wr1.y + hn.z * wr1.z + hn.w * wr1.w;
    // reduce over f4 (bits 0-1): full 16-col dot per jpair
    pa += __shfl_xor(pa, 1, 64); pa += __shfl_xor(pa, 2, 64);
    pb += __shfl_xor(pb, 1, 64); pb += __shfl_xor(pb, 2, 64);

    float h2a = fmaxf(pa + b2_l[j0], 0.f);
    float h2b = fmaxf(pb + b2_l[j0 + 1], 0.f);
    float w = h2a * W_lin[j0] + h2b * W_lin[j0 + 1];
    // reduce over jpair (bits 2-5)
    #pragma unroll
    for (int off = 4; off <= 32; off <<= 1) w += __shfl_xor(w, off, 64);
    if (lane == 0) out[n] = w + b_lin[0];
}

extern "C" void kernel_launch(void* const* d_in, const int* in_sizes, int n_in,
                              void* d_out, int out_size, void* d_ws, size_t ws_size,
                              hipStream_t stream) {
    const float* x       = (const float*)d_in[0];
    const int*   ei      = (const int*)  d_in[1];
    const int*   reg_id  = (const int*)  d_in[2];
    const int*   dep_id  = (const int*)  d_in[3];
    const float* W_feat  = (const float*)d_in[4];
    const float* b_feat  = (const float*)d_in[5];
    const float* reg_emb = (const float*)d_in[6];
    const float* dep_emb = (const float*)d_in[7];
    const float* W1_l    = (const float*)d_in[8];
    const float* b1_l    = (const float*)d_in[9];
    const float* W1_r    = (const float*)d_in[10];
    const float* W2_l    = (const float*)d_in[11];
    const float* b2_l    = (const float*)d_in[12];
    const float* W2_r    = (const float*)d_in[13];
    const float* W_lin   = (const float*)d_in[14];
    const float* b_lin   = (const float*)d_in[15];
    float* out = (float*)d_out;
    float* ws  = (float*)d_ws;

    const int N = N_NODES;
    float* p1 = ws;                      // [N,16]
    float* r1 = ws + 16 * N;             // [N,16]
    float* h1 = ws + 32 * N;             // [N,16]
    int* ideg  = (int*)(ws + 48 * N);    // [N]
    int* rowp  = ideg + N;               // [N]
    int* rank  = ideg + 2 * N;           // [E]
    int* csrc  = rank + N_EDGES;         // [E]
    int* parts = csrc + N_EDGES;         // [64]
    int* poff  = parts + 64;             // [64]

    hipMemsetAsync(ideg, 0, (size_t)N * sizeof(int), stream);

    node1_kernel<<<(N + 63) / 64, 256, 0, stream>>>(
        x, reg_id, dep_id, W_feat, b_feat, reg_emb, dep_emb, W1_l, W1_r, p1, r1);

    hist_kernel<<<(N_EDGES + 255) / 256, 256, 0, stream>>>(ei, ideg, rank);
    scan1_kernel<<<SCAN_NBLK, SCAN_BLK, 0, stream>>>(ideg, rowp, parts);
    scan2_kernel<<<1, 64, 0, stream>>>(parts, poff);
    scan3_kernel<<<SCAN_NBLK, SCAN_BLK, 0, stream>>>(rowp, poff);
    fill_kernel<<<(N_EDGES + 255) / 256, 256, 0, stream>>>(ei, rowp, rank, csrc);

    gather1_kernel<<<(N * 64 + 255) / 256, 256, 0, stream>>>(
        rowp, csrc, p1, r1, b1_l, h1);

    gather2_kernel<<<(N * 64 + 255) / 256, 256, 0, stream>>>(
        rowp, csrc, h1, W2_l, b2_l, W2_r, W_lin, b_lin, out);
}